// Round 11
// baseline (55.174 us; speedup 1.0000x reference)
//
#include <hip/hip_runtime.h>
#include <stdint.h>

// Problem constants (fixed by the reference: B=2048, K=6144, MU=2,
// G0 = 1 + D^2 (feedback), G1 = 1 + D + D^2 (parity)).
#define KLEN  6144
#define BROWS 2048
#define NG    (BROWS / 32)      // 64 bit-groups of 32 rows
#define GK    (NG * KLEN)       // u32 words per packed plane = 393216
#define NT    256               // threads per block (pack/ends)

// ends kernel: per-(enc,g) row scan, chunk CL=24 (EVEN -> M^CL = I)
#define CLE   24                // KLEN / 256

// emit tiling: block = (g, tile of ET3 t's); parities computed inline.
#define ET3   768               // tile length; 768/CLE = 32 -> tile starts on chunk bounds
#define NTILE (KLEN / ET3)      // 8
#define NT3   384               // emit threads; CL3 = 2 t's per thread (EVEN)
#define EMIT_GRID (NG * NTILE)  // 512 blocks
#define QROW  (3 * ET3 / 4)     // 576 float4-quads per row-tile (= 9 x 64: wave-aligned)
#define QPB   (32 * QROW)       // 18432 quads per block -> 48 iters @ 384 thr

typedef float vfloat4 __attribute__((ext_vector_type(4)));  // native vec for nt ops

// RSC recursion (bitwise over 32 rows packed in a u32):
//   fb = u ^ s1;  par = u ^ s0;  (s0,s1) <- (fb, s0)
// Linear part M satisfies M^2 = I, so for even-length chunks the actual chunk
// init = XOR of preceding chunks' zero-init end states (used at BOTH levels:
// ends kernel chunk=24, emit inline chunk=2, tile=768 — all even).
//
// Round-6 post-mortem: cooperative grid.sync() ~190 us/barrier — plain
// dispatches are the cheap grid barrier. Round-10 post-mortem: plane-fetch
// redundancy was free (L3); this round removes the planes entirely instead.

// ---------------------------------------------------------------------------
// Kernel A: bit-pack bits[B][K] -> packedS[g*K + t] (bit j = row g*32+j).
__global__ __launch_bounds__(NT) void pack_kernel(const float* __restrict__ bits,
                                                  uint32_t* __restrict__ packedS) {
    int task = blockIdx.x * NT + threadIdx.x;    // [0, GK/4)
    int g  = task / (KLEN / 4);
    int tq = task - g * (KLEN / 4);
    const float* rb = bits + (size_t)g * 32 * KLEN + 4 * tq;
    uint32_t w0 = 0, w1 = 0, w2 = 0, w3 = 0;
#pragma unroll 1
    for (int j0 = 0; j0 < 32; j0 += 8) {
#pragma unroll
        for (int j = 0; j < 8; ++j) {
            float4 f = *(const float4*)(rb + (size_t)(j0 + j) * KLEN);
            w0 |= (f.x > 0.5f ? 1u : 0u) << (j0 + j);
            w1 |= (f.y > 0.5f ? 1u : 0u) << (j0 + j);
            w2 |= (f.z > 0.5f ? 1u : 0u) << (j0 + j);
            w3 |= (f.w > 0.5f ? 1u : 0u) << (j0 + j);
        }
    }
    *(uint4*)(packedS + g * KLEN + 4 * tq) = make_uint4(w0, w1, w2, w3);
}

// ---------------------------------------------------------------------------
// Kernel B: tile-boundary states. Block = (enc, g); thread c owns chunk c
// (CLE=24 steps, zero-init) -> Hillis-Steele XOR prefix -> threads at tile
// boundaries (c multiple of 32) write the exclusive state to ends[].
__global__ __launch_bounds__(NT) void ends_kernel(const uint32_t* __restrict__ packedS,
                                                  const int* __restrict__ perm,
                                                  uint32_t* __restrict__ ends) {
    __shared__ uint32_t a0[NT], a1[NT];
    int c   = threadIdx.x;
    int enc = blockIdx.x >> 6;        // 0 or 1
    int g   = blockIdx.x & (NG - 1);
    const uint32_t* base = packedS + g * KLEN;
    int t0 = c * CLE;

    uint32_t s0 = 0, s1 = 0;
    if (enc) {
#pragma unroll
        for (int i = 0; i < CLE; ++i) {
            uint32_t u = base[perm[t0 + i]];
            uint32_t n0 = u ^ s1; s1 = s0; s0 = n0;
        }
    } else {
#pragma unroll
        for (int i = 0; i < CLE; ++i) {
            uint32_t u = base[t0 + i];
            uint32_t n0 = u ^ s1; s1 = s0; s0 = n0;
        }
    }

    a0[c] = s0; a1[c] = s1;
    __syncthreads();
#pragma unroll
    for (int off = 1; off < NT; off <<= 1) {
        uint32_t x0 = 0, x1 = 0;
        if (c >= off) { x0 = a0[c - off]; x1 = a1[c - off]; }
        __syncthreads();
        a0[c] ^= x0; a1[c] ^= x1;
        __syncthreads();
    }
    if ((c & 31) == 0) {              // t0 = c*24 = tile*768
        int tile = c >> 5;
        int idx = ((enc * NG + g) * NTILE + tile) * 2;
        ends[idx + 0] = c ? a0[c - 1] : 0u;
        ends[idx + 1] = c ? a1[c - 1] : 0u;
    }
}

// ---------------------------------------------------------------------------
// Kernel C: emit with INLINE parity. Block = (g, tile), 384 threads; thread i
// owns t-pair {tb+2i, tb+2i+1}. Loads sys pair (coalesced) + perm-gathered
// pair; 9-round block XOR-prefix for both encoders; parities -> LDS; then
// emit 32 rows x 576 quads as wave-contiguous 1 KB nontemporal float4 stores.
__global__ __launch_bounds__(NT3) void emit_kernel(const uint32_t* __restrict__ packedS,
                                                   const int* __restrict__ perm,
                                                   const uint32_t* __restrict__ ends,
                                                   float* __restrict__ out) {
    __shared__ uint32_t l0[ET3], l1[ET3], l2[ET3];
    __shared__ uint32_t c0[NT3], c1[NT3], d0[NT3], d1[NT3];
    int i    = threadIdx.x;
    int g    = blockIdx.x / NTILE;
    int tile = blockIdx.x - g * NTILE;
    const uint32_t* base = packedS + g * KLEN;
    int tb = tile * ET3;
    int ta = tb + 2 * i;

    uint32_t ua = base[ta], ub = base[ta + 1];           // enc1 inputs (direct)
    uint32_t va = base[perm[ta]], vb = base[perm[ta + 1]]; // enc2 inputs (gather)
    l0[2 * i] = ua; l0[2 * i + 1] = ub;

    // zero-init 2-step chunk end states: enc1 = (ub, ua), enc2 = (vb, va)
    c0[i] = ub; c1[i] = ua; d0[i] = vb; d1[i] = va;
    __syncthreads();
#pragma unroll
    for (int off = 1; off < NT3; off <<= 1) {
        uint32_t x0 = 0, x1 = 0, y0 = 0, y1 = 0;
        if (i >= off) { x0 = c0[i - off]; x1 = c1[i - off];
                        y0 = d0[i - off]; y1 = d1[i - off]; }
        __syncthreads();
        c0[i] ^= x0; c1[i] ^= x1; d0[i] ^= y0; d1[i] ^= y1;
        __syncthreads();
    }

    // thread init = tile init (from ends kernel) XOR exclusive block prefix
    int eidx = (g * NTILE + tile) * 2;                    // enc1
    int fidx = ((NG + g) * NTILE + tile) * 2;             // enc2
    uint32_t s0 = (i ? c0[i - 1] : 0u) ^ ends[eidx + 0];
    uint32_t s1 = (i ? c1[i - 1] : 0u) ^ ends[eidx + 1];
    uint32_t q0 = (i ? d0[i - 1] : 0u) ^ ends[fidx + 0];
    uint32_t q1 = (i ? d1[i - 1] : 0u) ^ ends[fidx + 1];

    // 2-step parity: p[t] = u ^ s0 (pre-update); (s0,s1) <- (u^s1, s0)
    uint32_t p1a = ua ^ s0;
    uint32_t p1b = ub ^ (ua ^ s1);
    uint32_t p2a = va ^ q0;
    uint32_t p2b = vb ^ (va ^ q1);
    l1[2 * i] = p1a; l1[2 * i + 1] = p1b;
    l2[2 * i] = p2a; l2[2 * i + 1] = p2b;
    __syncthreads();

    // emit: idx -> (row, quad); 576 quads/row = 9 waves exactly, so each
    // wave's 64 lanes are contiguous within one row (1 KB nt store/instr).
    float* gout = out + (size_t)(g * 32) * (3 * KLEN) + (size_t)tile * (3 * ET3);
#pragma unroll 2
    for (int k = 0; k < QPB / NT3; ++k) {               // 48 iterations
        int idx  = k * NT3 + i;
        int row  = idx / QROW;                          // const-div (magic mul)
        int qq   = idx - row * QROW;
        int pos0 = 4 * qq;                              // [0, 2304)
        int t0   = pos0 / 3;                            // const-div
        int r0   = pos0 - 3 * t0;                       // t0+1 <= ET3-1 always
        uint32_t w00 = l0[t0],     w01 = l1[t0],     w02 = l2[t0];
        uint32_t w10 = l0[t0 + 1], w11 = l1[t0 + 1], w12 = l2[t0 + 1];
        // element s: pos=pos0+s, comp=(pos0+s)%3 (0=sys,1=p1,2=p2)
        uint32_t e0 = r0 == 0 ? w00 : (r0 == 1 ? w01 : w02);
        uint32_t e1 = r0 == 0 ? w01 : (r0 == 1 ? w02 : w10);
        uint32_t e2 = r0 == 0 ? w02 : (r0 == 1 ? w10 : w11);
        uint32_t e3 = r0 == 0 ? w10 : (r0 == 1 ? w11 : w12);
        int bit = row;
        vfloat4 f;
        f.x = (float)((e0 >> bit) & 1u);
        f.y = (float)((e1 >> bit) & 1u);
        f.z = (float)((e2 >> bit) & 1u);
        f.w = (float)((e3 >> bit) & 1u);
        __builtin_nontemporal_store(f,
            (vfloat4*)(gout + (size_t)row * (3 * KLEN) + pos0));
    }
}

// ---------------------------------------------------------------------------
extern "C" void kernel_launch(void* const* d_in, const int* in_sizes, int n_in,
                              void* d_out, int out_size, void* d_ws, size_t ws_size,
                              hipStream_t stream) {
    const float* bits = (const float*)d_in[0];   // [B*K] float 0/1
    const int*   perm = (const int*)d_in[1];     // [K] int32
    float* out = (float*)d_out;                  // [B * 3K] float

    uint32_t* ws = (uint32_t*)d_ws;
    uint32_t* packedS = ws;                      // [GK]
    uint32_t* ends    = ws + (size_t)GK;         // [2*NG*NTILE*2] = 2048 u32

    hipLaunchKernelGGL(pack_kernel, dim3(GK / 4 / NT), dim3(NT), 0, stream,
                       bits, packedS);
    hipLaunchKernelGGL(ends_kernel, dim3(2 * NG), dim3(NT), 0, stream,
                       packedS, perm, ends);
    hipLaunchKernelGGL(emit_kernel, dim3(EMIT_GRID), dim3(NT3), 0, stream,
                       packedS, perm, ends, out);
}

// Round 12
// 47.879 us; speedup vs baseline: 1.1524x; 1.1524x over previous
//
#include <hip/hip_runtime.h>
#include <stdint.h>

// Problem constants (fixed by the reference: B=2048, K=6144, MU=2,
// G0 = 1 + D^2 (feedback), G1 = 1 + D + D^2 (parity)).
#define KLEN  6144
#define BROWS 2048
#define NG    (BROWS / 32)      // 64 bit-groups of 32 rows
#define GK    (NG * KLEN)       // u32 words per packed plane = 393216
#define NT    256               // threads per block (pack/emit)

// scan: 512-thread blocks, thread-chunk CL2=12 (EVEN — required so M^CL == I)
#define NT2   512
#define CL2   (KLEN / NT2)      // 12

// emit tiling: block = (g, tile of ET t's, quartet of 4 rows)
#define ET    1024
#define NTILE (KLEN / ET)       // 6
#define RPB   4                 // rows per block
#define NRS   (32 / RPB)        // 8
#define EMIT_GRID (NG * NTILE * NRS)   // 3072 blocks ≈ 12/CU queued

typedef float vfloat4 __attribute__((ext_vector_type(4)));  // native vec for nt ops

// RSC recursion (bitwise over 32 rows packed in a u32):
//   fb = u ^ s1;  par = u ^ s0;  (s0,s1) <- (fb, s0)
// State map's linear part M satisfies M^2 = I, so for even-length chunks the
// actual chunk init = XOR of preceding chunks' zero-init end states.
//
// Post-mortems: r6 — cooperative grid.sync() ~190 us/barrier; plain
// dispatches are the cheap grid barrier. r10/r11 — emit scales with
// block count (store-stream depth), NOT with staging redundancy (L3
// absorbs the 4.7 MB planes at any replication). Hence: max emit blocks,
// redundant staging accepted.

// ---------------------------------------------------------------------------
// Kernel A: bit-pack bits[B][K] -> packedS[g*K + t] (bit j = row g*32+j).
// Thread = (g, quad-of-t): 32 plain float4 loads (measured-ceiling path),
// one uint4 store.
__global__ __launch_bounds__(NT) void pack_kernel(const float* __restrict__ bits,
                                                  uint32_t* __restrict__ packedS) {
    int task = blockIdx.x * NT + threadIdx.x;    // [0, GK/4)
    int g  = task / (KLEN / 4);
    int tq = task - g * (KLEN / 4);
    const float* rb = bits + (size_t)g * 32 * KLEN + 4 * tq;
    uint32_t w0 = 0, w1 = 0, w2 = 0, w3 = 0;
#pragma unroll 1
    for (int j0 = 0; j0 < 32; j0 += 8) {
#pragma unroll
        for (int j = 0; j < 8; ++j) {
            float4 f = *(const float4*)(rb + (size_t)(j0 + j) * KLEN);
            w0 |= (f.x > 0.5f ? 1u : 0u) << (j0 + j);
            w1 |= (f.y > 0.5f ? 1u : 0u) << (j0 + j);
            w2 |= (f.z > 0.5f ? 1u : 0u) << (j0 + j);
            w3 |= (f.w > 0.5f ? 1u : 0u) << (j0 + j);
        }
    }
    *(uint4*)(packedS + g * KLEN + 4 * tq) = make_uint4(w0, w1, w2, w3);
}

// ---------------------------------------------------------------------------
// Kernel B: fused parallel scan. Block = (enc, g), 512 threads; thread c owns
// chunk c (CL2=12 steps). Zero-init scan -> end states; block-wide XOR prefix
// (Hillis-Steele in LDS, 9 rounds); rescan from corrected init using
// register-cached u[], emit packed parities as aligned uint4 stores.
__global__ __launch_bounds__(NT2) void scan_kernel(const uint32_t* __restrict__ packedS,
                                                   const int* __restrict__ perm,
                                                   uint32_t* __restrict__ p1,
                                                   uint32_t* __restrict__ p2) {
    __shared__ uint32_t a0[NT2], a1[NT2];
    int c   = threadIdx.x;
    int enc = blockIdx.x >> 6;        // 0 or 1
    int g   = blockIdx.x & (NG - 1);
    const uint32_t* base = packedS + g * KLEN;
    int t0 = c * CL2;

    uint32_t u[CL2];
    if (enc) {
#pragma unroll
        for (int i = 0; i < CL2; ++i) u[i] = base[perm[t0 + i]];
    } else {
#pragma unroll
        for (int i = 0; i < CL2; ++i) u[i] = base[t0 + i];
    }

    // zero-init chunk scan -> end state
    uint32_t s0 = 0, s1 = 0;
#pragma unroll
    for (int i = 0; i < CL2; ++i) { uint32_t n0 = u[i] ^ s1; s1 = s0; s0 = n0; }

    // block-wide XOR prefix (Hillis-Steele), then exclusive
    a0[c] = s0; a1[c] = s1;
    __syncthreads();
#pragma unroll
    for (int off = 1; off < NT2; off <<= 1) {
        uint32_t x0 = 0, x1 = 0;
        if (c >= off) { x0 = a0[c - off]; x1 = a1[c - off]; }
        __syncthreads();
        a0[c] ^= x0; a1[c] ^= x1;
        __syncthreads();
    }
    s0 = c ? a0[c - 1] : 0u;
    s1 = c ? a1[c - 1] : 0u;

    // rescan with actual init, emit packed parities (uint4 every 4 steps)
    uint32_t* __restrict__ pout = enc ? p2 : p1;
    uint32_t pq0, pq1, pq2;
#pragma unroll
    for (int i = 0; i < CL2; ++i) {
        uint32_t pv = u[i] ^ s0;
        uint32_t n0 = u[i] ^ s1; s1 = s0; s0 = n0;
        if ((i & 3) == 0) pq0 = pv;
        else if ((i & 3) == 1) pq1 = pv;
        else if ((i & 3) == 2) pq2 = pv;
        else *(uint4*)(pout + g * KLEN + t0 + i - 3) = make_uint4(pq0, pq1, pq2, pv);
    }
}

// ---------------------------------------------------------------------------
// Kernel C: emit codeword [sys, p1, p2] interleaved. Block = (g, tile,
// row-quartet): stage 3x ET plane words in LDS (uint4-coalesced, 12 KB),
// then emit 4 rows x 768 quads. Stores: wave-contiguous 1 KB nontemporal
// float4. 3072 blocks keep the store queue deep.
__global__ __launch_bounds__(NT) void emit_kernel(const uint32_t* __restrict__ ps,
                                                  const uint32_t* __restrict__ p1,
                                                  const uint32_t* __restrict__ p2,
                                                  float* __restrict__ out) {
    __shared__ uint32_t l0[ET], l1[ET], l2[ET];
    int blk  = blockIdx.x;
    int g    = blk / (NTILE * NRS);
    int rem  = blk - g * (NTILE * NRS);
    int tile = rem / NRS;
    int rs   = rem - tile * NRS;          // row-quartet index
    int i    = threadIdx.x;

    size_t pbase = (size_t)g * KLEN + (size_t)tile * ET;
    *(uint4*)(l0 + 4 * i) = *(const uint4*)(ps + pbase + 4 * i);
    *(uint4*)(l1 + 4 * i) = *(const uint4*)(p1 + pbase + 4 * i);
    *(uint4*)(l2 + 4 * i) = *(const uint4*)(p2 + pbase + 4 * i);
    __syncthreads();

#pragma unroll 1
    for (int rr = 0; rr < RPB; ++rr) {
        int bit = rs * RPB + rr;                    // row within group = shift
        int b   = g * 32 + bit;
        float* rowout = out + (size_t)b * (3 * KLEN) + (size_t)tile * (3 * ET);
#pragma unroll
        for (int k = 0; k < 3; ++k) {
            int qq   = i + NT * k;                  // quad in [0, 768)
            int pos0 = 4 * qq;                      // position in [0, 3072)
            int t0   = pos0 / 3;                    // compiler magic-mul
            int r0   = pos0 - 3 * t0;
            uint32_t w00 = l0[t0],     w01 = l1[t0],     w02 = l2[t0];
            uint32_t w10 = l0[t0 + 1], w11 = l1[t0 + 1], w12 = l2[t0 + 1];
            // element s: pos=pos0+s, comp=(pos0+s)%3 (0=sys,1=p1,2=p2)
            uint32_t e0 = r0 == 0 ? w00 : (r0 == 1 ? w01 : w02);
            uint32_t e1 = r0 == 0 ? w01 : (r0 == 1 ? w02 : w10);
            uint32_t e2 = r0 == 0 ? w02 : (r0 == 1 ? w10 : w11);
            uint32_t e3 = r0 == 0 ? w10 : (r0 == 1 ? w11 : w12);
            vfloat4 f;
            f.x = (float)((e0 >> bit) & 1u);
            f.y = (float)((e1 >> bit) & 1u);
            f.z = (float)((e2 >> bit) & 1u);
            f.w = (float)((e3 >> bit) & 1u);
            __builtin_nontemporal_store(f, (vfloat4*)(rowout + (size_t)pos0));
        }
    }
}

// ---------------------------------------------------------------------------
extern "C" void kernel_launch(void* const* d_in, const int* in_sizes, int n_in,
                              void* d_out, int out_size, void* d_ws, size_t ws_size,
                              hipStream_t stream) {
    const float* bits = (const float*)d_in[0];   // [B*K] float 0/1
    const int*   perm = (const int*)d_in[1];     // [K] int32
    float* out = (float*)d_out;                  // [B * 3K] float

    uint32_t* ws = (uint32_t*)d_ws;
    uint32_t* packedS = ws;                      // [GK]
    uint32_t* p1      = ws + (size_t)GK;         // [GK]
    uint32_t* p2      = ws + (size_t)2 * GK;     // [GK]

    hipLaunchKernelGGL(pack_kernel, dim3(GK / 4 / NT), dim3(NT), 0, stream,
                       bits, packedS);
    hipLaunchKernelGGL(scan_kernel, dim3(2 * NG), dim3(NT2), 0, stream,
                       packedS, perm, p1, p2);
    hipLaunchKernelGGL(emit_kernel, dim3(EMIT_GRID), dim3(NT), 0, stream,
                       packedS, p1, p2, out);
}

// Round 13
// 47.470 us; speedup vs baseline: 1.1623x; 1.0086x over previous
//
#include <hip/hip_runtime.h>
#include <stdint.h>

// Problem constants (fixed by the reference: B=2048, K=6144, MU=2,
// G0 = 1 + D^2 (feedback), G1 = 1 + D + D^2 (parity)).
#define KLEN  6144
#define BROWS 2048
#define NG    (BROWS / 32)      // 64 bit-groups of 32 rows
#define GK    (NG * KLEN)       // u32 words per packed plane = 393216
#define NT    256               // threads per block (pack/emit)

// scan: 512-thread blocks, thread-chunk CL2=12 (EVEN — required so M^CL == I)
#define NT2   512
#define CL2   (KLEN / NT2)      // 12

// emit tiling: block = (g, tile of ET t's, pair of 2 rows)
#define ET    1024
#define NTILE (KLEN / ET)       // 6
#define RPB   2                 // rows per block
#define NRS   (32 / RPB)        // 16
#define EMIT_GRID (NG * NTILE * NRS)   // 6144 blocks ≈ 24/CU queued

typedef float vfloat4 __attribute__((ext_vector_type(4)));  // native vec for nt ops

// RSC recursion (bitwise over 32 rows packed in a u32):
//   fb = u ^ s1;  par = u ^ s0;  (s0,s1) <- (fb, s0)
// State map's linear part M satisfies M^2 = I, so for even-length chunks the
// actual chunk init = XOR of preceding chunks' zero-init end states.
//
// Post-mortems: r6 — cooperative grid.sync() ~190 us/barrier; plain
// dispatches are the cheap grid barrier. r10-r12 — emit scales with block
// count (store-stream depth): 512 blk = 53-55 us, 1536 = 49.8, 3072 = 47.9.
// Staging redundancy is L3-absorbed and free. This round: 6144 blocks.

// ---------------------------------------------------------------------------
// Kernel A: bit-pack bits[B][K] -> packedS[g*K + t] (bit j = row g*32+j).
// Thread = (g, quad-of-t): 32 plain float4 loads (measured-ceiling path),
// one uint4 store.
__global__ __launch_bounds__(NT) void pack_kernel(const float* __restrict__ bits,
                                                  uint32_t* __restrict__ packedS) {
    int task = blockIdx.x * NT + threadIdx.x;    // [0, GK/4)
    int g  = task / (KLEN / 4);
    int tq = task - g * (KLEN / 4);
    const float* rb = bits + (size_t)g * 32 * KLEN + 4 * tq;
    uint32_t w0 = 0, w1 = 0, w2 = 0, w3 = 0;
#pragma unroll 1
    for (int j0 = 0; j0 < 32; j0 += 8) {
#pragma unroll
        for (int j = 0; j < 8; ++j) {
            float4 f = *(const float4*)(rb + (size_t)(j0 + j) * KLEN);
            w0 |= (f.x > 0.5f ? 1u : 0u) << (j0 + j);
            w1 |= (f.y > 0.5f ? 1u : 0u) << (j0 + j);
            w2 |= (f.z > 0.5f ? 1u : 0u) << (j0 + j);
            w3 |= (f.w > 0.5f ? 1u : 0u) << (j0 + j);
        }
    }
    *(uint4*)(packedS + g * KLEN + 4 * tq) = make_uint4(w0, w1, w2, w3);
}

// ---------------------------------------------------------------------------
// Kernel B: fused parallel scan. Block = (enc, g), 512 threads; thread c owns
// chunk c (CL2=12 steps). Zero-init scan -> end states; block-wide XOR prefix
// (Hillis-Steele in LDS, 9 rounds); rescan from corrected init using
// register-cached u[], emit packed parities as aligned uint4 stores.
__global__ __launch_bounds__(NT2) void scan_kernel(const uint32_t* __restrict__ packedS,
                                                   const int* __restrict__ perm,
                                                   uint32_t* __restrict__ p1,
                                                   uint32_t* __restrict__ p2) {
    __shared__ uint32_t a0[NT2], a1[NT2];
    int c   = threadIdx.x;
    int enc = blockIdx.x >> 6;        // 0 or 1
    int g   = blockIdx.x & (NG - 1);
    const uint32_t* base = packedS + g * KLEN;
    int t0 = c * CL2;

    uint32_t u[CL2];
    if (enc) {
#pragma unroll
        for (int i = 0; i < CL2; ++i) u[i] = base[perm[t0 + i]];
    } else {
#pragma unroll
        for (int i = 0; i < CL2; ++i) u[i] = base[t0 + i];
    }

    // zero-init chunk scan -> end state
    uint32_t s0 = 0, s1 = 0;
#pragma unroll
    for (int i = 0; i < CL2; ++i) { uint32_t n0 = u[i] ^ s1; s1 = s0; s0 = n0; }

    // block-wide XOR prefix (Hillis-Steele), then exclusive
    a0[c] = s0; a1[c] = s1;
    __syncthreads();
#pragma unroll
    for (int off = 1; off < NT2; off <<= 1) {
        uint32_t x0 = 0, x1 = 0;
        if (c >= off) { x0 = a0[c - off]; x1 = a1[c - off]; }
        __syncthreads();
        a0[c] ^= x0; a1[c] ^= x1;
        __syncthreads();
    }
    s0 = c ? a0[c - 1] : 0u;
    s1 = c ? a1[c - 1] : 0u;

    // rescan with actual init, emit packed parities (uint4 every 4 steps)
    uint32_t* __restrict__ pout = enc ? p2 : p1;
    uint32_t pq0, pq1, pq2;
#pragma unroll
    for (int i = 0; i < CL2; ++i) {
        uint32_t pv = u[i] ^ s0;
        uint32_t n0 = u[i] ^ s1; s1 = s0; s0 = n0;
        if ((i & 3) == 0) pq0 = pv;
        else if ((i & 3) == 1) pq1 = pv;
        else if ((i & 3) == 2) pq2 = pv;
        else *(uint4*)(pout + g * KLEN + t0 + i - 3) = make_uint4(pq0, pq1, pq2, pv);
    }
}

// ---------------------------------------------------------------------------
// Kernel C: emit codeword [sys, p1, p2] interleaved. Block = (g, tile,
// row-pair): stage 3x ET plane words in LDS (uint4-coalesced, 12 KB), then
// emit 2 rows x 768 quads. Stores: wave-contiguous 1 KB nontemporal float4.
// 6144 blocks keep the store queue deep.
__global__ __launch_bounds__(NT) void emit_kernel(const uint32_t* __restrict__ ps,
                                                  const uint32_t* __restrict__ p1,
                                                  const uint32_t* __restrict__ p2,
                                                  float* __restrict__ out) {
    __shared__ uint32_t l0[ET], l1[ET], l2[ET];
    int blk  = blockIdx.x;
    int g    = blk / (NTILE * NRS);
    int rem  = blk - g * (NTILE * NRS);
    int tile = rem / NRS;
    int rs   = rem - tile * NRS;          // row-pair index
    int i    = threadIdx.x;

    size_t pbase = (size_t)g * KLEN + (size_t)tile * ET;
    *(uint4*)(l0 + 4 * i) = *(const uint4*)(ps + pbase + 4 * i);
    *(uint4*)(l1 + 4 * i) = *(const uint4*)(p1 + pbase + 4 * i);
    *(uint4*)(l2 + 4 * i) = *(const uint4*)(p2 + pbase + 4 * i);
    __syncthreads();

#pragma unroll 1
    for (int rr = 0; rr < RPB; ++rr) {
        int bit = rs * RPB + rr;                    // row within group = shift
        int b   = g * 32 + bit;
        float* rowout = out + (size_t)b * (3 * KLEN) + (size_t)tile * (3 * ET);
#pragma unroll
        for (int k = 0; k < 3; ++k) {
            int qq   = i + NT * k;                  // quad in [0, 768)
            int pos0 = 4 * qq;                      // position in [0, 3072)
            int t0   = pos0 / 3;                    // compiler magic-mul
            int r0   = pos0 - 3 * t0;
            uint32_t w00 = l0[t0],     w01 = l1[t0],     w02 = l2[t0];
            uint32_t w10 = l0[t0 + 1], w11 = l1[t0 + 1], w12 = l2[t0 + 1];
            // element s: pos=pos0+s, comp=(pos0+s)%3 (0=sys,1=p1,2=p2)
            uint32_t e0 = r0 == 0 ? w00 : (r0 == 1 ? w01 : w02);
            uint32_t e1 = r0 == 0 ? w01 : (r0 == 1 ? w02 : w10);
            uint32_t e2 = r0 == 0 ? w02 : (r0 == 1 ? w10 : w11);
            uint32_t e3 = r0 == 0 ? w10 : (r0 == 1 ? w11 : w12);
            vfloat4 f;
            f.x = (float)((e0 >> bit) & 1u);
            f.y = (float)((e1 >> bit) & 1u);
            f.z = (float)((e2 >> bit) & 1u);
            f.w = (float)((e3 >> bit) & 1u);
            __builtin_nontemporal_store(f, (vfloat4*)(rowout + (size_t)pos0));
        }
    }
}

// ---------------------------------------------------------------------------
extern "C" void kernel_launch(void* const* d_in, const int* in_sizes, int n_in,
                              void* d_out, int out_size, void* d_ws, size_t ws_size,
                              hipStream_t stream) {
    const float* bits = (const float*)d_in[0];   // [B*K] float 0/1
    const int*   perm = (const int*)d_in[1];     // [K] int32
    float* out = (float*)d_out;                  // [B * 3K] float

    uint32_t* ws = (uint32_t*)d_ws;
    uint32_t* packedS = ws;                      // [GK]
    uint32_t* p1      = ws + (size_t)GK;         // [GK]
    uint32_t* p2      = ws + (size_t)2 * GK;     // [GK]

    hipLaunchKernelGGL(pack_kernel, dim3(GK / 4 / NT), dim3(NT), 0, stream,
                       bits, packedS);
    hipLaunchKernelGGL(scan_kernel, dim3(2 * NG), dim3(NT2), 0, stream,
                       packedS, perm, p1, p2);
    hipLaunchKernelGGL(emit_kernel, dim3(EMIT_GRID), dim3(NT), 0, stream,
                       packedS, p1, p2, out);
}